// Round 3
// baseline (454.255 us; speedup 1.0000x reference)
//
#include <hip/hip_runtime.h>
#include <math.h>

// B=8, N=4096, S=512, C=16, D=1024, E=256, H=1024, V=100000
// d_out (float32): [0]=loss, [1..65536]=scores (8,512,16), [65537..69632]=preds

typedef short short8 __attribute__((ext_vector_type(8)));
typedef float f32x16 __attribute__((ext_vector_type(16)));

static __device__ inline unsigned short f2bf(float x) {
  unsigned u = __float_as_uint(x);
  unsigned r = (u + 0x7FFFu + ((u >> 16) & 1u)) >> 16;
  return (unsigned short)r;
}
static __device__ inline float bf2f(unsigned short b) {
  return __uint_as_float(((unsigned)b) << 16);
}

#define GLD_TO_LDS(gp, lp)                                          \
  __builtin_amdgcn_global_load_lds(                                 \
      (const __attribute__((address_space(1))) void*)(gp),          \
      (__attribute__((address_space(3))) void*)(lp), 16, 0, 0)

// ---------------------------------------------------------------------------
// Prep: candidate ids + span source rows.
// ---------------------------------------------------------------------------
__global__ __launch_bounds__(256) void k_prep2(const int* __restrict__ linker,
                                               const int* __restrict__ cand_all,
                                               int* __restrict__ cand_ids,
                                               int* __restrict__ span_rows) {
  int g = blockIdx.x * 256 + threadIdx.x;  // [0, 65536)
  int pair = g >> 4;
  int b = pair >> 9;
  int i = linker[pair];
  cand_ids[g] = cand_all[(((size_t)b << 12) + (size_t)i) * 16 + (g & 15)];
  if (g < 4096) span_rows[g] = ((g >> 9) << 12) + linker[g];
}

// ---------------------------------------------------------------------------
// Gather rows and split fp32 -> bf16 hi/lo.  LOG4: log2(rowlen/4).
// ---------------------------------------------------------------------------
template <int LOG4>
__global__ __launch_bounds__(256) void k_gsplit(const float* __restrict__ src,
                                                const int* __restrict__ rows,
                                                unsigned short* __restrict__ hi,
                                                unsigned short* __restrict__ lo) {
  int f = blockIdx.x * 256 + threadIdx.x;  // one float4
  int row = f >> LOG4;
  int c4 = f & ((1 << LOG4) - 1);
  const float4 v =
      *((const float4*)(src + ((size_t)rows[row] << (LOG4 + 2))) + c4);
  unsigned short h0 = f2bf(v.x), h1 = f2bf(v.y), h2 = f2bf(v.z), h3 = f2bf(v.w);
  unsigned short l0 = f2bf(v.x - bf2f(h0)), l1 = f2bf(v.y - bf2f(h1));
  unsigned short l2 = f2bf(v.z - bf2f(h2)), l3 = f2bf(v.w - bf2f(h3));
  *(ushort4*)(hi + ((size_t)f << 2)) = make_ushort4(h0, h1, h2, h3);
  *(ushort4*)(lo + ((size_t)f << 2)) = make_ushort4(l0, l1, l2, l3);
}

// ---------------------------------------------------------------------------
// W1 (1280x1024) -> transposed bf16 splits.
// ---------------------------------------------------------------------------
__global__ __launch_bounds__(256) void k_w1t(const float* __restrict__ W1,
                                             unsigned short* __restrict__ sThi,
                                             unsigned short* __restrict__ sTlo,
                                             unsigned short* __restrict__ eThi,
                                             unsigned short* __restrict__ eTlo) {
  __shared__ float t[32][33];
  int n0 = blockIdx.x * 32, k0 = blockIdx.y * 32;
  int rr = threadIdx.x >> 5, cc = threadIdx.x & 31;
#pragma unroll
  for (int i = 0; i < 4; ++i)
    t[rr + 8 * i][cc] = W1[(size_t)(k0 + rr + 8 * i) * 1024 + n0 + cc];
  __syncthreads();
#pragma unroll
  for (int i = 0; i < 4; ++i) {
    int nl = rr + 8 * i;
    float v = t[cc][nl];
    unsigned short h = f2bf(v);
    unsigned short l = f2bf(v - bf2f(h));
    int n = n0 + nl, k = k0 + cc;
    if (k0 < 1024) {
      sThi[(size_t)n * 1024 + k] = h;
      sTlo[(size_t)n * 1024 + k] = l;
    } else {
      eThi[(size_t)n * 256 + (k - 1024)] = h;
      eTlo[(size_t)n * 256 + (k - 1024)] = l;
    }
  }
}

// ---------------------------------------------------------------------------
// Split-2 bf16 MFMA GEMM on 32x32x16, 128x128 tile, 8 K-steps of 32.
// 256 threads = 4 waves (2x2), wave microtile 64x64 (2x2 tiles of 32x32).
// Grid 1-D, XCD-swizzled: id = m8 + 8*c + 64*q; all 8 col-blocks of one
// A row-tile share id%8 (same XCD) and sit within 56 dispatch slots.
// MODE 0 (GEMM1): g=8q+m8, r=g>>2, ksplit=g&3 (K-offset 256*ksplit);
//                 epilogue atomicAdd acc into Out[m*1024+n] (Hs, pre-zeroed).
// MODE 1 (GEMM2): r=8q+m8 (0..511), koff=0;
//                 epilogue relu(acc+Hs+b1).W2 row-sums -> atomicAdd Out[m].
// ---------------------------------------------------------------------------
template <int RLA, int RLB, int MODE>
__global__ __launch_bounds__(256, 4) void k_g32(
    const unsigned short* __restrict__ Ahi, const unsigned short* __restrict__ Alo,
    const unsigned short* __restrict__ Bhi, const unsigned short* __restrict__ Blo,
    const float* __restrict__ HsIn, const float* __restrict__ b1,
    const float* __restrict__ W2, float* __restrict__ Out) {
  const int tid = threadIdx.x;
  const int l = tid & 63;
  const int w = tid >> 6;        // 0..3
  const int wm = w >> 1, wn = w & 1;
  const int id = blockIdx.x;
  const int m8 = id & 7;
  const int c = (id >> 3) & 7;
  const int q = id >> 6;
  int row0, koff;
  if (MODE == 1) {
    row0 = ((q << 3) + m8) << 7;
    koff = 0;
  } else {
    int g = (q << 3) + m8;       // 0..127 = r*4+s
    row0 = (g >> 2) << 7;
    koff = (g & 3) << 8;
  }
  const int col0 = c << 7;

  // Ahi[0..4095] | Alo[4096..] | Bhi[8192..] | Blo[12288..]  (ushorts, 32KB)
  __shared__ unsigned short lds[16384];

  f32x16 acc[2][2];
#pragma unroll
  for (int i = 0; i < 2; ++i)
#pragma unroll
    for (int j = 0; j < 2; ++j)
#pragma unroll
      for (int k = 0; k < 16; ++k) acc[i][j][k] = 0.f;

  // Staging: 512 16B-chunks per region; thread stages chunks tid and tid+256.
  // Chunk g: row=g>>2, phys slot=g&3, logical chunk = phys ^ ((row>>1)&3).
  const int ar0 = tid >> 2, ap0 = tid & 3;
  const int al0c = ap0 ^ ((ar0 >> 1) & 3);
  const int ar1 = (tid + 256) >> 2;
  const int al1c = ap0 ^ ((ar1 >> 1) & 3);
  const size_t aoff0 = (size_t)(row0 + ar0) * RLA + koff + al0c * 8;
  const size_t aoff1 = (size_t)(row0 + ar1) * RLA + koff + al1c * 8;
  const size_t boff0 = (size_t)(col0 + ar0) * RLB + koff + al0c * 8;
  const size_t boff1 = (size_t)(col0 + ar1) * RLB + koff + al1c * 8;
  unsigned short* const lw0 = lds + w * 512;         // chunk tid
  unsigned short* const lw1 = lds + 2048 + w * 512;  // chunk tid+256

  for (int ks = 0; ks < 8; ++ks) {
    const int k0 = ks * 32;
    if (ks) __syncthreads();
    GLD_TO_LDS(Ahi + aoff0 + k0, lw0);
    GLD_TO_LDS(Ahi + aoff1 + k0, lw1);
    GLD_TO_LDS(Alo + aoff0 + k0, lw0 + 4096);
    GLD_TO_LDS(Alo + aoff1 + k0, lw1 + 4096);
    GLD_TO_LDS(Bhi + boff0 + k0, lw0 + 8192);
    GLD_TO_LDS(Bhi + boff1 + k0, lw1 + 8192);
    GLD_TO_LDS(Blo + boff0 + k0, lw0 + 12288);
    GLD_TO_LDS(Blo + boff1 + k0, lw1 + 12288);
    __syncthreads();

#pragma unroll
    for (int kc = 0; kc < 2; ++kc) {
      // 32x32x16 A-frag: lane holds A[m=l&31][k=(l>>5)*8+j]
      const int kg = kc * 2 + (l >> 5);
      short8 ah[2], alv[2], bh[2], bl[2];
#pragma unroll
      for (int it = 0; it < 2; ++it) {
        int r = wm * 64 + it * 32 + (l & 31);
        int off = r * 32 + ((kg ^ ((r >> 1) & 3)) << 3);
        ah[it] = *(const short8*)(lds + off);
        alv[it] = *(const short8*)(lds + 4096 + off);
      }
#pragma unroll
      for (int jt = 0; jt < 2; ++jt) {
        int r = wn * 64 + jt * 32 + (l & 31);
        int off = r * 32 + ((kg ^ ((r >> 1) & 3)) << 3);
        bh[jt] = *(const short8*)(lds + 8192 + off);
        bl[jt] = *(const short8*)(lds + 12288 + off);
      }
#pragma unroll
      for (int it = 0; it < 2; ++it)
#pragma unroll
        for (int jt = 0; jt < 2; ++jt) {
          acc[it][jt] = __builtin_amdgcn_mfma_f32_32x32x16_bf16(
              ah[it], bh[jt], acc[it][jt], 0, 0, 0);
          acc[it][jt] = __builtin_amdgcn_mfma_f32_32x32x16_bf16(
              ah[it], bl[jt], acc[it][jt], 0, 0, 0);
          acc[it][jt] = __builtin_amdgcn_mfma_f32_32x32x16_bf16(
              alv[it], bh[jt], acc[it][jt], 0, 0, 0);
        }
    }
  }

  // C/D layout (32x32): col = l&31, row = (rg&3) + 8*(rg>>2) + 4*(l>>5)
  if (MODE == 0) {
#pragma unroll
    for (int it = 0; it < 2; ++it) {
      int mb = row0 + wm * 64 + it * 32 + 4 * (l >> 5);
#pragma unroll
      for (int jt = 0; jt < 2; ++jt) {
        int n = col0 + wn * 64 + jt * 32 + (l & 31);
#pragma unroll
        for (int rg = 0; rg < 16; ++rg) {
          int m = mb + (rg & 3) + 8 * (rg >> 2);
          atomicAdd(&Out[(size_t)m * 1024 + n], acc[it][jt][rg]);
        }
      }
    }
  } else {
#pragma unroll
    for (int it = 0; it < 2; ++it) {
      float s[16];
#pragma unroll
      for (int rg = 0; rg < 16; ++rg) s[rg] = 0.f;
      const int p0 = (row0 + wm * 64 + it * 32) >> 4;  // pair of rows 0..15
#pragma unroll
      for (int jt = 0; jt < 2; ++jt) {
        int n = col0 + wn * 64 + jt * 32 + (l & 31);
        float b1v = b1[n], w2v = W2[n];
        float add0 = HsIn[(size_t)p0 * 1024 + n] + b1v;        // rows 0..15
        float add1 = HsIn[(size_t)(p0 + 1) * 1024 + n] + b1v;  // rows 16..31
#pragma unroll
        for (int rg = 0; rg < 16; ++rg) {
          float h = fmaxf(acc[it][jt][rg] + (rg < 8 ? add0 : add1), 0.f);
          s[rg] = fmaf(h, w2v, s[rg]);
        }
      }
#pragma unroll
      for (int st = 1; st < 32; st <<= 1)
#pragma unroll
        for (int rg = 0; rg < 16; ++rg) s[rg] += __shfl_xor(s[rg], st, 64);
      if ((l & 31) == 0) {
        int mb = row0 + wm * 64 + it * 32 + 4 * (l >> 5);
#pragma unroll
        for (int rg = 0; rg < 16; ++rg)
          atomicAdd(&Out[mb + (rg & 3) + 8 * (rg >> 2)], s[rg]);
      }
    }
  }
}

// ---------------------------------------------------------------------------
// Finalize: scores (+b2), masked BCE loss, argmax predictions.
// ---------------------------------------------------------------------------
__global__ __launch_bounds__(256) void k_final(const float* __restrict__ score_ws,
                                               const float* __restrict__ b2p,
                                               const float* __restrict__ targets_all,
                                               const int* __restrict__ linker,
                                               const int* __restrict__ len_all,
                                               float* __restrict__ out) {
  int p = blockIdx.x * 256 + threadIdx.x;  // [0, 4096)
  float b2 = b2p[0];
  int b = p >> 9;
  int i = linker[p];
  int len = len_all[(b << 12) + i];
  const float* tg = targets_all + ((((size_t)b << 12) + (size_t)i) << 4);

  float loss = 0.f;
  float best = -INFINITY;
  int bc = 0;
#pragma unroll
  for (int c = 0; c < 16; ++c) {
    float sc = score_ws[p * 16 + c] + b2;
    out[1 + p * 16 + c] = sc;
    float val;
    if (c < len) {
      float t = tg[c];
      loss += fmaxf(sc, 0.f) - sc * t + log1pf(expf(-fabsf(sc)));
      val = sc;
    } else {
      val = sc - 1e23f;
    }
    if (val > best) { best = val; bc = c; }
  }
  out[1 + 65536 + p] = (float)bc;

  for (int off = 32; off > 0; off >>= 1) loss += __shfl_down(loss, off, 64);
  if ((threadIdx.x & 63) == 0) atomicAdd(out, loss);
}

// ===========================================================================
// Fallback fp32 path (round-1, proven) — used if ws_size is too small.
// ===========================================================================
#define BM 128
#define BN 128
#define BK 16
#define PAD 4

__global__ __launch_bounds__(256) void k_prep(const int* __restrict__ linker,
                                              const int* __restrict__ cand_all,
                                              int* __restrict__ cand_ids) {
  int g = blockIdx.x * 256 + threadIdx.x;
  int pair = g >> 4;
  int c = g & 15;
  int b = pair >> 9;
  int i = linker[pair];
  cand_ids[g] = cand_all[(((size_t)b << 12) + (size_t)i) * 16 + c];
}

__global__ __launch_bounds__(256) void k_hs(const float* __restrict__ span,
                                            const float* __restrict__ W1,
                                            const int* __restrict__ linker,
                                            float* __restrict__ Hs) {
  const int tid = threadIdx.x;
  const int tx = tid & 15, ty = tid >> 4;
  const int row0 = blockIdx.y * BM;
  const int col0 = blockIdx.x * BN;
  __shared__ float As[BK][BM + PAD];
  __shared__ float Bs[BK][BN + PAD];
  __shared__ int rows_g[BM];
  if (tid < BM) {
    int m = row0 + tid;
    int b = m >> 9;
    rows_g[tid] = (b << 12) + linker[m];
  }
  __syncthreads();
  float acc[8][8] = {};
  for (int k0 = 0; k0 < 1024; k0 += BK) {
#pragma unroll
    for (int ll = 0; ll < 2; ++ll) {
      int f = tid + ll * 256;
      int r = f >> 2;
      int kk = (f & 3) << 2;
      const float4 v = *(const float4*)(span + (size_t)rows_g[r] * 1024 + k0 + kk);
      As[kk + 0][r] = v.x; As[kk + 1][r] = v.y;
      As[kk + 2][r] = v.z; As[kk + 3][r] = v.w;
    }
#pragma unroll
    for (int ll = 0; ll < 2; ++ll) {
      int f = tid + ll * 256;
      int kk = f >> 5;
      int nn = (f & 31) << 2;
      *(float4*)&Bs[kk][nn] = *(const float4*)(W1 + (size_t)(k0 + kk) * 1024 + col0 + nn);
    }
    __syncthreads();
#pragma unroll
    for (int k = 0; k < BK; ++k) {
      float a[8], b[8];
      *(float4*)&a[0] = *(const float4*)&As[k][ty * 8];
      *(float4*)&a[4] = *(const float4*)&As[k][ty * 8 + 4];
      *(float4*)&b[0] = *(const float4*)&Bs[k][tx * 8];
      *(float4*)&b[4] = *(const float4*)&Bs[k][tx * 8 + 4];
#pragma unroll
      for (int i = 0; i < 8; ++i)
#pragma unroll
        for (int j = 0; j < 8; ++j) acc[i][j] = fmaf(a[i], b[j], acc[i][j]);
    }
    __syncthreads();
  }
#pragma unroll
  for (int i = 0; i < 8; ++i) {
    int m = row0 + ty * 8 + i;
    float* dst = Hs + (size_t)m * 1024 + col0 + tx * 8;
    *(float4*)dst = *(float4*)&acc[i][0];
    *(float4*)(dst + 4) = *(float4*)&acc[i][4];
  }
}

__global__ __launch_bounds__(256) void k_hc(const float* __restrict__ ent,
                                            const float* __restrict__ W1,
                                            const int* __restrict__ cand_ids,
                                            const float* __restrict__ Hs,
                                            const float* __restrict__ b1,
                                            const float* __restrict__ W2,
                                            float* __restrict__ score_ws) {
  const int tid = threadIdx.x;
  const int tx = tid & 15, ty = tid >> 4;
  const int row0 = blockIdx.y * BM;
  const int col0 = blockIdx.x * BN;
  __shared__ float As[BK][BM + PAD];
  __shared__ float Bs[BK][BN + PAD];
  __shared__ int rows_g[BM];
  __shared__ float red[BM][17];
  if (tid < BM) rows_g[tid] = cand_ids[row0 + tid];
  __syncthreads();
  float acc[8][8] = {};
  for (int k0 = 0; k0 < 256; k0 += BK) {
#pragma unroll
    for (int ll = 0; ll < 2; ++ll) {
      int f = tid + ll * 256;
      int r = f >> 2;
      int kk = (f & 3) << 2;
      const float4 v = *(const float4*)(ent + (size_t)rows_g[r] * 256 + k0 + kk);
      As[kk + 0][r] = v.x; As[kk + 1][r] = v.y;
      As[kk + 2][r] = v.z; As[kk + 3][r] = v.w;
    }
#pragma unroll
    for (int ll = 0; ll < 2; ++ll) {
      int f = tid + ll * 256;
      int kk = f >> 5;
      int nn = (f & 31) << 2;
      *(float4*)&Bs[kk][nn] =
          *(const float4*)(W1 + (size_t)(1024 + k0 + kk) * 1024 + col0 + nn);
    }
    __syncthreads();
#pragma unroll
    for (int k = 0; k < BK; ++k) {
      float a[8], b[8];
      *(float4*)&a[0] = *(const float4*)&As[k][ty * 8];
      *(float4*)&a[4] = *(const float4*)&As[k][ty * 8 + 4];
      *(float4*)&b[0] = *(const float4*)&Bs[k][tx * 8];
      *(float4*)&b[4] = *(const float4*)&Bs[k][tx * 8 + 4];
#pragma unroll
      for (int i = 0; i < 8; ++i)
#pragma unroll
        for (int j = 0; j < 8; ++j) acc[i][j] = fmaf(a[i], b[j], acc[i][j]);
    }
    __syncthreads();
  }
  const int pair = (row0 + ty * 8) >> 4;
  float hsv[8], b1v[8], w2v[8];
  {
    const float* hp = Hs + (size_t)pair * 1024 + col0 + tx * 8;
    *(float4*)&hsv[0] = *(const float4*)hp;
    *(float4*)&hsv[4] = *(const float4*)(hp + 4);
    const float* bp = b1 + col0 + tx * 8;
    *(float4*)&b1v[0] = *(const float4*)bp;
    *(float4*)&b1v[4] = *(const float4*)(bp + 4);
    const float* wp = W2 + col0 + tx * 8;
    *(float4*)&w2v[0] = *(const float4*)wp;
    *(float4*)&w2v[4] = *(const float4*)(wp + 4);
  }
#pragma unroll
  for (int i = 0; i < 8; ++i) {
    float s = 0.f;
#pragma unroll
    for (int j = 0; j < 8; ++j) {
      float h = acc[i][j] + hsv[j] + b1v[j];
      h = fmaxf(h, 0.f);
      s = fmaf(h, w2v[j], s);
    }
    red[ty * 8 + i][tx] = s;
  }
  __syncthreads();
  if (tid < BM) {
    float s = 0.f;
#pragma unroll
    for (int x = 0; x < 16; ++x) s += red[tid][x];
    atomicAdd(&score_ws[row0 + tid], s);
  }
}

// ===========================================================================
extern "C" void kernel_launch(void* const* d_in, const int* in_sizes, int n_in,
                              void* d_out, int out_size, void* d_ws,
                              size_t ws_size, hipStream_t stream) {
  const float* span    = (const float*)d_in[0];
  const float* ent     = (const float*)d_in[1];
  const float* W1      = (const float*)d_in[2];
  const float* b1      = (const float*)d_in[3];
  const float* W2      = (const float*)d_in[4];
  const float* b2      = (const float*)d_in[5];
  const float* targets = (const float*)d_in[6];
  const int* linker    = (const int*)d_in[7];
  const int* cand_all  = (const int*)d_in[8];
  const int* len_all   = (const int*)d_in[9];
  float* out = (float*)d_out;

  char* ws = (char*)d_ws;
  float* Hs       = (float*)(ws + 0);            // 16,777,216 B
  float* score_ws = (float*)(ws + 16777216);     //    262,144 B
  int* cand_ids   = (int*)(ws + 17039360);       //    262,144 B
  int* span_rows  = (int*)(ws + 17301504);       //     16,384 B
  unsigned short* A1h  = (unsigned short*)(ws + 17317888);   // 8,388,608
  unsigned short* A1l  = (unsigned short*)(ws + 25706496);   // 8,388,608
  unsigned short* A2h  = (unsigned short*)(ws + 34095104);   // 33,554,432
  unsigned short* A2l  = (unsigned short*)(ws + 67649536);   // 33,554,432
  unsigned short* sTh  = (unsigned short*)(ws + 101203968);  // 2,097,152
  unsigned short* sTl  = (unsigned short*)(ws + 103301120);  // 2,097,152
  unsigned short* eTh  = (unsigned short*)(ws + 105398272);  //   524,288
  unsigned short* eTl  = (unsigned short*)(ws + 105922560);  //   524,288
  const size_t NEED_MFMA = 106446848;

  hipMemsetAsync(d_out, 0, sizeof(float), stream);
  hipMemsetAsync(score_ws, 0, 65536 * sizeof(float), stream);

  if (ws_size >= NEED_MFMA) {
    hipMemsetAsync(Hs, 0, 16777216, stream);  // split-K accumulates into Hs
    k_prep2<<<dim3(256), dim3(256), 0, stream>>>(linker, cand_all, cand_ids,
                                                 span_rows);
    k_gsplit<6><<<dim3(16384), dim3(256), 0, stream>>>(ent, cand_ids, A2h, A2l);
    k_gsplit<8><<<dim3(4096), dim3(256), 0, stream>>>(span, span_rows, A1h, A1l);
    k_w1t<<<dim3(32, 40), dim3(256), 0, stream>>>(W1, sTh, sTl, eTh, eTl);
    // GEMM1: Hs += gather(span)@W1s, split-K=4, 1024 blocks (4/CU)
    k_g32<1024, 1024, 0><<<dim3(1024), dim3(256), 0, stream>>>(
        A1h, A1l, sTh, sTl, nullptr, nullptr, nullptr, Hs);
    // GEMM2: fused hc + relu + W2 row-sums -> score_ws, 4096 blocks
    k_g32<256, 256, 1><<<dim3(4096), dim3(256), 0, stream>>>(
        A2h, A2l, eTh, eTl, Hs, b1, W2, score_ws);
  } else {
    k_prep<<<dim3(256), dim3(256), 0, stream>>>(linker, cand_all, cand_ids);
    dim3 g1(8, 32);
    k_hs<<<g1, dim3(256), 0, stream>>>(span, W1, linker, Hs);
    dim3 g2(8, 512);
    k_hc<<<g2, dim3(256), 0, stream>>>(ent, W1, cand_ids, Hs, b1, W2, score_ws);
  }

  k_final<<<dim3(16), dim3(256), 0, stream>>>(score_ws, b2, targets, linker,
                                              len_all, out);
}

// Round 4
// 419.533 us; speedup vs baseline: 1.0828x; 1.0828x over previous
//
#include <hip/hip_runtime.h>
#include <math.h>

// B=8, N=4096, S=512, C=16, D=1024, E=256, H=1024, V=100000
// d_out (float32): [0]=loss, [1..65536]=scores (8,512,16), [65537..69632]=preds

typedef short short8 __attribute__((ext_vector_type(8)));
typedef float f32x16 __attribute__((ext_vector_type(16)));

static __device__ inline unsigned short f2bf(float x) {
  unsigned u = __float_as_uint(x);
  unsigned r = (u + 0x7FFFu + ((u >> 16) & 1u)) >> 16;
  return (unsigned short)r;
}
static __device__ inline float bf2f(unsigned short b) {
  return __uint_as_float(((unsigned)b) << 16);
}

#define GLD_TO_LDS(gp, lp)                                          \
  __builtin_amdgcn_global_load_lds(                                 \
      (const __attribute__((address_space(1))) void*)(gp),          \
      (__attribute__((address_space(3))) void*)(lp), 16, 0, 0)

// ---------------------------------------------------------------------------
// Prep: candidate ids + span source rows.
// ---------------------------------------------------------------------------
__global__ __launch_bounds__(256) void k_prep2(const int* __restrict__ linker,
                                               const int* __restrict__ cand_all,
                                               int* __restrict__ cand_ids,
                                               int* __restrict__ span_rows) {
  int g = blockIdx.x * 256 + threadIdx.x;  // [0, 65536)
  int pair = g >> 4;
  int b = pair >> 9;
  int i = linker[pair];
  cand_ids[g] = cand_all[(((size_t)b << 12) + (size_t)i) * 16 + (g & 15)];
  if (g < 4096) span_rows[g] = ((g >> 9) << 12) + linker[g];
}

// ---------------------------------------------------------------------------
// Gather rows and split fp32 -> bf16 hi/lo.  LOG4: log2(rowlen/4).
// ---------------------------------------------------------------------------
template <int LOG4>
__global__ __launch_bounds__(256) void k_gsplit(const float* __restrict__ src,
                                                const int* __restrict__ rows,
                                                unsigned short* __restrict__ hi,
                                                unsigned short* __restrict__ lo) {
  int f = blockIdx.x * 256 + threadIdx.x;  // one float4
  int row = f >> LOG4;
  int c4 = f & ((1 << LOG4) - 1);
  const float4 v =
      *((const float4*)(src + ((size_t)rows[row] << (LOG4 + 2))) + c4);
  unsigned short h0 = f2bf(v.x), h1 = f2bf(v.y), h2 = f2bf(v.z), h3 = f2bf(v.w);
  unsigned short l0 = f2bf(v.x - bf2f(h0)), l1 = f2bf(v.y - bf2f(h1));
  unsigned short l2 = f2bf(v.z - bf2f(h2)), l3 = f2bf(v.w - bf2f(h3));
  *(ushort4*)(hi + ((size_t)f << 2)) = make_ushort4(h0, h1, h2, h3);
  *(ushort4*)(lo + ((size_t)f << 2)) = make_ushort4(l0, l1, l2, l3);
}

// ---------------------------------------------------------------------------
// W1 (1280x1024) -> transposed bf16 splits.
// ---------------------------------------------------------------------------
__global__ __launch_bounds__(256) void k_w1t(const float* __restrict__ W1,
                                             unsigned short* __restrict__ sThi,
                                             unsigned short* __restrict__ sTlo,
                                             unsigned short* __restrict__ eThi,
                                             unsigned short* __restrict__ eTlo) {
  __shared__ float t[32][33];
  int n0 = blockIdx.x * 32, k0 = blockIdx.y * 32;
  int rr = threadIdx.x >> 5, cc = threadIdx.x & 31;
#pragma unroll
  for (int i = 0; i < 4; ++i)
    t[rr + 8 * i][cc] = W1[(size_t)(k0 + rr + 8 * i) * 1024 + n0 + cc];
  __syncthreads();
#pragma unroll
  for (int i = 0; i < 4; ++i) {
    int nl = rr + 8 * i;
    float v = t[cc][nl];
    unsigned short h = f2bf(v);
    unsigned short l = f2bf(v - bf2f(h));
    int n = n0 + nl, k = k0 + cc;
    if (k0 < 1024) {
      sThi[(size_t)n * 1024 + k] = h;
      sTlo[(size_t)n * 1024 + k] = l;
    } else {
      eThi[(size_t)n * 256 + (k - 1024)] = h;
      eTlo[(size_t)n * 256 + (k - 1024)] = l;
    }
  }
}

// ---------------------------------------------------------------------------
// Split-2 bf16 MFMA GEMM on 32x32x16, 128x128 tile, BK=32, KSTEPS steps.
// 256 threads = 4 waves (2x2), wave microtile 64x64 (2x2 tiles of 32x32).
// Grid 1-D XCD-swizzled: id = m8 + 8*cb + 64*q; row-tile r=(q<<3)+m8; all
// 8 col-blocks of one row-tile share id%8 (same XCD).
// MODE 0 (GEMM1): plain stores acc -> Out[m*1024+n].        grid 256, K=1024
// MODE 1 (GEMM2): relu(acc+Hs+b1).W2 row-sums via LDS transpose-reduce ->
//                 plain store Out[cb*65536 + m] (per-colblock partials).
//                 grid 4096, K=256.
// ---------------------------------------------------------------------------
template <int KSTEPS, int RLA, int RLB, int MODE>
__global__ __launch_bounds__(256, 4) void k_g32(
    const unsigned short* __restrict__ Ahi, const unsigned short* __restrict__ Alo,
    const unsigned short* __restrict__ Bhi, const unsigned short* __restrict__ Blo,
    const float* __restrict__ HsIn, const float* __restrict__ b1,
    const float* __restrict__ W2, float* __restrict__ Out) {
  const int tid = threadIdx.x;
  const int l = tid & 63;
  const int w = tid >> 6;        // 0..3
  const int wm = w >> 1, wn = w & 1;
  const int id = blockIdx.x;
  const int m8 = id & 7;
  const int cb = (id >> 3) & 7;
  const int q = id >> 6;
  const int row0 = ((q << 3) + m8) << 7;
  const int col0 = cb << 7;

  // Ahi[0..4095] | Alo[4096..] | Bhi[8192..] | Blo[12288..]  (ushorts, 32KB)
  __shared__ unsigned short lds[16384];

  f32x16 acc[2][2];
#pragma unroll
  for (int i = 0; i < 2; ++i)
#pragma unroll
    for (int j = 0; j < 2; ++j)
#pragma unroll
      for (int k = 0; k < 16; ++k) acc[i][j][k] = 0.f;

  // Staging: 512 16B-chunks per region; thread stages chunks tid and tid+256.
  // Chunk g: row=g>>2, phys slot=g&3, logical chunk = phys ^ ((row>>1)&3).
  const int ar0 = tid >> 2, ap0 = tid & 3;
  const int al0c = ap0 ^ ((ar0 >> 1) & 3);
  const int ar1 = (tid + 256) >> 2;
  const int al1c = ap0 ^ ((ar1 >> 1) & 3);
  const size_t aoff0 = (size_t)(row0 + ar0) * RLA + al0c * 8;
  const size_t aoff1 = (size_t)(row0 + ar1) * RLA + al1c * 8;
  const size_t boff0 = (size_t)(col0 + ar0) * RLB + al0c * 8;
  const size_t boff1 = (size_t)(col0 + ar1) * RLB + al1c * 8;
  unsigned short* const lw0 = lds + w * 512;         // chunk tid
  unsigned short* const lw1 = lds + 2048 + w * 512;  // chunk tid+256

  for (int ks = 0; ks < KSTEPS; ++ks) {
    const int k0 = ks * 32;
    if (ks) __syncthreads();
    GLD_TO_LDS(Ahi + aoff0 + k0, lw0);
    GLD_TO_LDS(Ahi + aoff1 + k0, lw1);
    GLD_TO_LDS(Alo + aoff0 + k0, lw0 + 4096);
    GLD_TO_LDS(Alo + aoff1 + k0, lw1 + 4096);
    GLD_TO_LDS(Bhi + boff0 + k0, lw0 + 8192);
    GLD_TO_LDS(Bhi + boff1 + k0, lw1 + 8192);
    GLD_TO_LDS(Blo + boff0 + k0, lw0 + 12288);
    GLD_TO_LDS(Blo + boff1 + k0, lw1 + 12288);
    __syncthreads();

#pragma unroll
    for (int kc = 0; kc < 2; ++kc) {
      // 32x32x16 A-frag: lane holds A[m=l&31][k=(l>>5)*8+j]
      const int kg = kc * 2 + (l >> 5);
      short8 ah[2], alv[2], bh[2], bl[2];
#pragma unroll
      for (int it = 0; it < 2; ++it) {
        int r = wm * 64 + it * 32 + (l & 31);
        int off = r * 32 + ((kg ^ ((r >> 1) & 3)) << 3);
        ah[it] = *(const short8*)(lds + off);
        alv[it] = *(const short8*)(lds + 4096 + off);
      }
#pragma unroll
      for (int jt = 0; jt < 2; ++jt) {
        int r = wn * 64 + jt * 32 + (l & 31);
        int off = r * 32 + ((kg ^ ((r >> 1) & 3)) << 3);
        bh[jt] = *(const short8*)(lds + 8192 + off);
        bl[jt] = *(const short8*)(lds + 12288 + off);
      }
#pragma unroll
      for (int it = 0; it < 2; ++it)
#pragma unroll
        for (int jt = 0; jt < 2; ++jt) {
          acc[it][jt] = __builtin_amdgcn_mfma_f32_32x32x16_bf16(
              ah[it], bh[jt], acc[it][jt], 0, 0, 0);
          acc[it][jt] = __builtin_amdgcn_mfma_f32_32x32x16_bf16(
              ah[it], bl[jt], acc[it][jt], 0, 0, 0);
          acc[it][jt] = __builtin_amdgcn_mfma_f32_32x32x16_bf16(
              alv[it], bh[jt], acc[it][jt], 0, 0, 0);
        }
    }
  }

  // C/D layout (32x32): col = l&31, row = (rg&3) + 8*(rg>>2) + 4*(l>>5)
  if (MODE == 0) {
#pragma unroll
    for (int it = 0; it < 2; ++it) {
      int mb = row0 + wm * 64 + it * 32 + 4 * (l >> 5);
#pragma unroll
      for (int jt = 0; jt < 2; ++jt) {
        int n = col0 + wn * 64 + jt * 32 + (l & 31);
#pragma unroll
        for (int rg = 0; rg < 16; ++rg) {
          int m = mb + (rg & 3) + 8 * (rg >> 2);
          Out[(size_t)m * 1024 + n] = acc[it][jt][rg];
        }
      }
    }
  } else {
    // Fused epilogue: per-lane partial scores, then LDS transpose-reduce.
    float sv[2][16];
#pragma unroll
    for (int it = 0; it < 2; ++it) {
#pragma unroll
      for (int rg = 0; rg < 16; ++rg) sv[it][rg] = 0.f;
      const int p0 = (row0 + wm * 64 + it * 32) >> 4;  // 16-row pair index
#pragma unroll
      for (int jt = 0; jt < 2; ++jt) {
        int n = col0 + wn * 64 + jt * 32 + (l & 31);
        float b1v = b1[n], w2v = W2[n];
        float add0 = HsIn[(size_t)p0 * 1024 + n] + b1v;        // rows 0..15
        float add1 = HsIn[(size_t)(p0 + 1) * 1024 + n] + b1v;  // rows 16..31
#pragma unroll
        for (int rg = 0; rg < 16; ++rg) {
          float h = fmaxf(acc[it][jt][rg] + (rg < 8 ? add0 : add1), 0.f);
          sv[it][rg] = fmaf(h, w2v, sv[it][rg]);
        }
      }
    }
    __syncthreads();  // K-loop LDS reads complete; reuse lds as f32 scratch
    float* scf = (float*)lds;  // [8 slots][32 rows][32 cols], rotation-swizzled
    const int cc0 = l & 31, lh4 = 4 * (l >> 5);
#pragma unroll
    for (int it = 0; it < 2; ++it)
#pragma unroll
      for (int rg = 0; rg < 16; ++rg) {
        int row = (rg & 3) + 8 * (rg >> 2) + lh4;  // 0..31 within tile
        scf[((w * 2 + it) * 32 + row) * 32 + ((cc0 + row) & 31)] = sv[it][rg];
      }
    __syncthreads();
    // 256 threads: 2 per global row gr (halves of 32 cols), sum wn=0 + wn=1.
    int gr = tid >> 1, h = tid & 1;
    int r = gr & 31, itv = (gr >> 5) & 1, wmv = gr >> 6;
    const float* sa = scf + ((wmv * 4 + itv) * 32 + r) * 32;      // wn=0 slot
    const float* sb = scf + ((wmv * 4 + 2 + itv) * 32 + r) * 32;  // wn=1 slot
    float sum = 0.f;
#pragma unroll
    for (int j = 0; j < 16; ++j) {
      int cidx = (h * 16 + j + r) & 31;
      sum += sa[cidx] + sb[cidx];
    }
    sum += __shfl_xor(sum, 1, 64);
    if (h == 0) Out[(size_t)cb * 65536 + row0 + gr] = sum;
  }
}

// ---------------------------------------------------------------------------
// Finalize: sum 8 col-block partials, +b2; masked BCE loss; argmax preds.
// ---------------------------------------------------------------------------
__global__ __launch_bounds__(256) void k_final8(const float* __restrict__ score8,
                                                const float* __restrict__ b2p,
                                                const float* __restrict__ targets_all,
                                                const int* __restrict__ linker,
                                                const int* __restrict__ len_all,
                                                float* __restrict__ out) {
  int p = blockIdx.x * 256 + threadIdx.x;  // [0, 4096)
  float b2 = b2p[0];
  int b = p >> 9;
  int i = linker[p];
  int len = len_all[(b << 12) + i];
  const float* tg = targets_all + ((((size_t)b << 12) + (size_t)i) << 4);

  float loss = 0.f;
  float best = -INFINITY;
  int bc = 0;
#pragma unroll
  for (int c = 0; c < 16; ++c) {
    float sc = b2;
#pragma unroll
    for (int c8 = 0; c8 < 8; ++c8) sc += score8[c8 * 65536 + p * 16 + c];
    out[1 + p * 16 + c] = sc;
    float val;
    if (c < len) {
      float t = tg[c];
      loss += fmaxf(sc, 0.f) - sc * t + log1pf(expf(-fabsf(sc)));
      val = sc;
    } else {
      val = sc - 1e23f;
    }
    if (val > best) { best = val; bc = c; }
  }
  out[1 + 65536 + p] = (float)bc;

  for (int off = 32; off > 0; off >>= 1) loss += __shfl_down(loss, off, 64);
  if ((threadIdx.x & 63) == 0) atomicAdd(out, loss);
}

// ===========================================================================
// Fallback fp32 path (round-1, proven) — used if ws_size is too small.
// ===========================================================================
#define BM 128
#define BN 128
#define BK 16
#define PAD 4

__global__ __launch_bounds__(256) void k_prep(const int* __restrict__ linker,
                                              const int* __restrict__ cand_all,
                                              int* __restrict__ cand_ids) {
  int g = blockIdx.x * 256 + threadIdx.x;
  int pair = g >> 4;
  int c = g & 15;
  int b = pair >> 9;
  int i = linker[pair];
  cand_ids[g] = cand_all[(((size_t)b << 12) + (size_t)i) * 16 + c];
}

__global__ __launch_bounds__(256) void k_hs(const float* __restrict__ span,
                                            const float* __restrict__ W1,
                                            const int* __restrict__ linker,
                                            float* __restrict__ Hs) {
  const int tid = threadIdx.x;
  const int tx = tid & 15, ty = tid >> 4;
  const int row0 = blockIdx.y * BM;
  const int col0 = blockIdx.x * BN;
  __shared__ float As[BK][BM + PAD];
  __shared__ float Bs[BK][BN + PAD];
  __shared__ int rows_g[BM];
  if (tid < BM) {
    int m = row0 + tid;
    int b = m >> 9;
    rows_g[tid] = (b << 12) + linker[m];
  }
  __syncthreads();
  float acc[8][8] = {};
  for (int k0 = 0; k0 < 1024; k0 += BK) {
#pragma unroll
    for (int ll = 0; ll < 2; ++ll) {
      int f = tid + ll * 256;
      int r = f >> 2;
      int kk = (f & 3) << 2;
      const float4 v = *(const float4*)(span + (size_t)rows_g[r] * 1024 + k0 + kk);
      As[kk + 0][r] = v.x; As[kk + 1][r] = v.y;
      As[kk + 2][r] = v.z; As[kk + 3][r] = v.w;
    }
#pragma unroll
    for (int ll = 0; ll < 2; ++ll) {
      int f = tid + ll * 256;
      int kk = f >> 5;
      int nn = (f & 31) << 2;
      *(float4*)&Bs[kk][nn] = *(const float4*)(W1 + (size_t)(k0 + kk) * 1024 + col0 + nn);
    }
    __syncthreads();
#pragma unroll
    for (int k = 0; k < BK; ++k) {
      float a[8], b[8];
      *(float4*)&a[0] = *(const float4*)&As[k][ty * 8];
      *(float4*)&a[4] = *(const float4*)&As[k][ty * 8 + 4];
      *(float4*)&b[0] = *(const float4*)&Bs[k][tx * 8];
      *(float4*)&b[4] = *(const float4*)&Bs[k][tx * 8 + 4];
#pragma unroll
      for (int i = 0; i < 8; ++i)
#pragma unroll
        for (int j = 0; j < 8; ++j) acc[i][j] = fmaf(a[i], b[j], acc[i][j]);
    }
    __syncthreads();
  }
#pragma unroll
  for (int i = 0; i < 8; ++i) {
    int m = row0 + ty * 8 + i;
    float* dst = Hs + (size_t)m * 1024 + col0 + tx * 8;
    *(float4*)dst = *(float4*)&acc[i][0];
    *(float4*)(dst + 4) = *(float4*)&acc[i][4];
  }
}

__global__ __launch_bounds__(256) void k_hc(const float* __restrict__ ent,
                                            const float* __restrict__ W1,
                                            const int* __restrict__ cand_ids,
                                            const float* __restrict__ Hs,
                                            const float* __restrict__ b1,
                                            const float* __restrict__ W2,
                                            float* __restrict__ score_ws) {
  const int tid = threadIdx.x;
  const int tx = tid & 15, ty = tid >> 4;
  const int row0 = blockIdx.y * BM;
  const int col0 = blockIdx.x * BN;
  __shared__ float As[BK][BM + PAD];
  __shared__ float Bs[BK][BN + PAD];
  __shared__ int rows_g[BM];
  __shared__ float red[BM][17];
  if (tid < BM) rows_g[tid] = cand_ids[row0 + tid];
  __syncthreads();
  float acc[8][8] = {};
  for (int k0 = 0; k0 < 256; k0 += BK) {
#pragma unroll
    for (int ll = 0; ll < 2; ++ll) {
      int f = tid + ll * 256;
      int r = f >> 2;
      int kk = (f & 3) << 2;
      const float4 v = *(const float4*)(ent + (size_t)rows_g[r] * 256 + k0 + kk);
      As[kk + 0][r] = v.x; As[kk + 1][r] = v.y;
      As[kk + 2][r] = v.z; As[kk + 3][r] = v.w;
    }
#pragma unroll
    for (int ll = 0; ll < 2; ++ll) {
      int f = tid + ll * 256;
      int kk = f >> 5;
      int nn = (f & 31) << 2;
      *(float4*)&Bs[kk][nn] =
          *(const float4*)(W1 + (size_t)(1024 + k0 + kk) * 1024 + col0 + nn);
    }
    __syncthreads();
#pragma unroll
    for (int k = 0; k < BK; ++k) {
      float a[8], b[8];
      *(float4*)&a[0] = *(const float4*)&As[k][ty * 8];
      *(float4*)&a[4] = *(const float4*)&As[k][ty * 8 + 4];
      *(float4*)&b[0] = *(const float4*)&Bs[k][tx * 8];
      *(float4*)&b[4] = *(const float4*)&Bs[k][tx * 8 + 4];
#pragma unroll
      for (int i = 0; i < 8; ++i)
#pragma unroll
        for (int j = 0; j < 8; ++j) acc[i][j] = fmaf(a[i], b[j], acc[i][j]);
    }
    __syncthreads();
  }
  const int pair = (row0 + ty * 8) >> 4;
  float hsv[8], b1v[8], w2v[8];
  {
    const float* hp = Hs + (size_t)pair * 1024 + col0 + tx * 8;
    *(float4*)&hsv[0] = *(const float4*)hp;
    *(float4*)&hsv[4] = *(const float4*)(hp + 4);
    const float* bp = b1 + col0 + tx * 8;
    *(float4*)&b1v[0] = *(const float4*)bp;
    *(float4*)&b1v[4] = *(const float4*)(bp + 4);
    const float* wp = W2 + col0 + tx * 8;
    *(float4*)&w2v[0] = *(const float4*)wp;
    *(float4*)&w2v[4] = *(const float4*)(wp + 4);
  }
#pragma unroll
  for (int i = 0; i < 8; ++i) {
    float s = 0.f;
#pragma unroll
    for (int j = 0; j < 8; ++j) {
      float h = acc[i][j] + hsv[j] + b1v[j];
      h = fmaxf(h, 0.f);
      s = fmaf(h, w2v[j], s);
    }
    red[ty * 8 + i][tx] = s;
  }
  __syncthreads();
  if (tid < BM) {
    float s = 0.f;
#pragma unroll
    for (int x = 0; x < 16; ++x) s += red[tid][x];
    atomicAdd(&score_ws[row0 + tid], s);
  }
}

__global__ __launch_bounds__(256) void k_final(const float* __restrict__ score_ws,
                                               const float* __restrict__ b2p,
                                               const float* __restrict__ targets_all,
                                               const int* __restrict__ linker,
                                               const int* __restrict__ len_all,
                                               float* __restrict__ out) {
  int p = blockIdx.x * 256 + threadIdx.x;  // [0, 4096)
  float b2 = b2p[0];
  int b = p >> 9;
  int i = linker[p];
  int len = len_all[(b << 12) + i];
  const float* tg = targets_all + ((((size_t)b << 12) + (size_t)i) << 4);

  float loss = 0.f;
  float best = -INFINITY;
  int bc = 0;
#pragma unroll
  for (int c = 0; c < 16; ++c) {
    float sc = score_ws[p * 16 + c] + b2;
    out[1 + p * 16 + c] = sc;
    float val;
    if (c < len) {
      float t = tg[c];
      loss += fmaxf(sc, 0.f) - sc * t + log1pf(expf(-fabsf(sc)));
      val = sc;
    } else {
      val = sc - 1e23f;
    }
    if (val > best) { best = val; bc = c; }
  }
  out[1 + 65536 + p] = (float)bc;

  for (int off = 32; off > 0; off >>= 1) loss += __shfl_down(loss, off, 64);
  if ((threadIdx.x & 63) == 0) atomicAdd(out, loss);
}

// ===========================================================================
extern "C" void kernel_launch(void* const* d_in, const int* in_sizes, int n_in,
                              void* d_out, int out_size, void* d_ws,
                              size_t ws_size, hipStream_t stream) {
  const float* span    = (const float*)d_in[0];
  const float* ent     = (const float*)d_in[1];
  const float* W1      = (const float*)d_in[2];
  const float* b1      = (const float*)d_in[3];
  const float* W2      = (const float*)d_in[4];
  const float* b2      = (const float*)d_in[5];
  const float* targets = (const float*)d_in[6];
  const int* linker    = (const int*)d_in[7];
  const int* cand_all  = (const int*)d_in[8];
  const int* len_all   = (const int*)d_in[9];
  float* out = (float*)d_out;

  char* ws = (char*)d_ws;
  float* Hs       = (float*)(ws + 0);            // 16,777,216 B
  float* score_ws = (float*)(ws + 16777216);     //    262,144 B (fallback)
  int* cand_ids   = (int*)(ws + 17039360);       //    262,144 B
  int* span_rows  = (int*)(ws + 17301504);       //     16,384 B
  unsigned short* A1h  = (unsigned short*)(ws + 17317888);   // 8,388,608
  unsigned short* A1l  = (unsigned short*)(ws + 25706496);   // 8,388,608
  unsigned short* A2h  = (unsigned short*)(ws + 34095104);   // 33,554,432
  unsigned short* A2l  = (unsigned short*)(ws + 67649536);   // 33,554,432
  unsigned short* sTh  = (unsigned short*)(ws + 101203968);  // 2,097,152
  unsigned short* sTl  = (unsigned short*)(ws + 103301120);  // 2,097,152
  unsigned short* eTh  = (unsigned short*)(ws + 105398272);  //   524,288
  unsigned short* eTl  = (unsigned short*)(ws + 105922560);  //   524,288
  const size_t NEED_MFMA = 106446848;
  // score8[8][65536] (2 MB) aliases A1h: A1 is dead after GEMM1 completes,
  // GEMM2 (the only writer of score8) is stream-ordered after GEMM1.
  float* score8 = (float*)A1h;

  hipMemsetAsync(d_out, 0, sizeof(float), stream);

  if (ws_size >= NEED_MFMA) {
    k_prep2<<<dim3(256), dim3(256), 0, stream>>>(linker, cand_all, cand_ids,
                                                 span_rows);
    k_gsplit<6><<<dim3(16384), dim3(256), 0, stream>>>(ent, cand_ids, A2h, A2l);
    k_gsplit<8><<<dim3(4096), dim3(256), 0, stream>>>(span, span_rows, A1h, A1l);
    k_w1t<<<dim3(32, 40), dim3(256), 0, stream>>>(W1, sTh, sTl, eTh, eTl);
    // GEMM1: Hs = gather(span)@W1s, 256 blocks, plain stores
    k_g32<32, 1024, 1024, 0><<<dim3(256), dim3(256), 0, stream>>>(
        A1h, A1l, sTh, sTl, nullptr, nullptr, nullptr, Hs);
    // GEMM2: fused hc + relu + W2 row-sums -> score8 partials, 4096 blocks
    k_g32<8, 256, 256, 1><<<dim3(4096), dim3(256), 0, stream>>>(
        A2h, A2l, eTh, eTl, Hs, b1, W2, score8);
    k_final8<<<dim3(16), dim3(256), 0, stream>>>(score8, b2, targets, linker,
                                                 len_all, out);
  } else {
    hipMemsetAsync(score_ws, 0, 65536 * sizeof(float), stream);
    k_prep<<<dim3(256), dim3(256), 0, stream>>>(linker, cand_all, cand_ids);
    dim3 g1(8, 32);
    k_hs<<<g1, dim3(256), 0, stream>>>(span, W1, linker, Hs);
    dim3 g2(8, 512);
    k_hc<<<g2, dim3(256), 0, stream>>>(ent, W1, cand_ids, Hs, b1, W2, score_ws);
    k_final<<<dim3(16), dim3(256), 0, stream>>>(score_ws, b2, targets, linker,
                                                len_all, out);
  }
}